// Round 9
// baseline (214.838 us; speedup 1.0000x reference)
//
#include <hip/hip_runtime.h>

// ============================================================================
// theta batch-uniform => M = U^dag Z0 U fixed. Product input state =>
// ev(b) = F1(b)^T * A * F2(b), A = alpha[243 x 27] over {I,Z,Y} strings,
// F1 = m0⊗..⊗m4 (243), F2 = m5⊗m6⊗m7 (27), m_w = {1, cos x_w, -sin x_w}.
//
// SINGLE fused kernel, 512 blocks x 256 threads (all co-resident: LDS 36KB
// -> 4 blk/CU, launch_bounds(256,2) -> >=2 blk/CU => 512 resident, so
// ws-flag spin sync is deadlock-free without cooperative launch).
//   blocks 0-15 : zero DD slice -> flagZ; enumerate 1/16 of strings, scatter
//                 into global dense DD -> flagA; gather own sub-tensor,
//                 6-stage LDS PTM transform -> Rg -> flagB.
//   block 16    : wait flagB, wire-1/wire-0 transforms, write AF -> READY.
//   ALL blocks  : wait READY, stage AF via LDS (relaxed atomics, cross-XCD
//                 safe), then MFMA+VALU contraction, 4 groups/wave.
// ============================================================================

typedef _Float16 v8hf __attribute__((ext_vector_type(8)));
typedef float v4f __attribute__((ext_vector_type(4)));

#define MAGIC 0x13572468

struct cpx { float re, im; };
__device__ __forceinline__ cpx cmul(cpx a, cpx b) {
    return {a.re * b.re - a.im * b.im, a.re * b.im + a.im * b.re};
}

__device__ __forceinline__ cpx pget(int a, int i, int j) {
    static const float RE[4][4] = {{1, 0, 0, 1}, {0, 1, 1, 0},
                                   {0, 0, 0, 0}, {1, 0, 0, -1}};
    static const float IM[4][4] = {{0, 0, 0, 0}, {0, 0, 0, 0},
                                   {0, -1, 1, 0}, {0, 0, 0, 0}};
    cpx r; r.re = RE[a][i * 2 + j]; r.im = IM[a][i * 2 + j];
    return r;
}

// PTM entry (gate g = l*8+w, row a, col b) = 0.5 Re Tr(sig_b G^dag sig_a G)
__device__ float ptm_entry(const float* __restrict__ theta, int g, int a, int b) {
    const int l = g >> 3, w = g & 7;
    const float phi = theta[(l * 8 + w) * 3 + 0];
    const float th  = theta[(l * 8 + w) * 3 + 1];
    const float om  = theta[(l * 8 + w) * 3 + 2];
    const float c = cosf(0.5f * th), s = sinf(0.5f * th);
    const float ps = 0.5f * (phi + om), ms = 0.5f * (phi - om);
    cpx G[2][2];
    G[0][0] = {c * cosf(ps), -c * sinf(ps)};
    G[0][1] = {-s * cosf(ms), -s * sinf(ms)};
    G[1][0] = {s * cosf(ms), -s * sinf(ms)};
    G[1][1] = {c * cosf(ps), c * sinf(ps)};
    cpx M1[2][2], H[2][2];
#pragma unroll
    for (int i = 0; i < 2; ++i)
#pragma unroll
        for (int j = 0; j < 2; ++j) {
            cpx acc{0.f, 0.f};
#pragma unroll
            for (int k = 0; k < 2; ++k) {
                cpx t = cmul(pget(a, i, k), G[k][j]);
                acc.re += t.re; acc.im += t.im;
            }
            M1[i][j] = acc;
        }
#pragma unroll
    for (int i = 0; i < 2; ++i)
#pragma unroll
        for (int j = 0; j < 2; ++j) {
            cpx acc{0.f, 0.f};
#pragma unroll
            for (int k = 0; k < 2; ++k) {
                cpx gc{G[k][i].re, -G[k][i].im};
                cpx t = cmul(gc, M1[k][j]);
                acc.re += t.re; acc.im += t.im;
            }
            H[i][j] = acc;
        }
    float tr = 0.f;
#pragma unroll
    for (int i = 0; i < 2; ++i)
#pragma unroll
        for (int j = 0; j < 2; ++j) {
            cpx pb = pget(b, i, j);
            tr += pb.re * H[j][i].re - pb.im * H[j][i].im;
        }
    return 0.5f * tr;
}

__device__ void cnot_entry(int pr, int cand, int* CIDX, float* CSGN) {
    const int pc = pr >> 2, pt = pr & 3;
    const int a = cand >> 2, b2 = cand & 3;
    const int perm[4] = {0, 1, 3, 2};
    float ov = 0.f;
#pragma unroll
    for (int r = 0; r < 4; ++r)
#pragma unroll
        for (int c2 = 0; c2 < 4; ++c2) {
            const int rp = perm[r], cp = perm[c2];
            cpx Rv = cmul(pget(pc, rp >> 1, cp >> 1), pget(pt, rp & 1, cp & 1));
            cpx Kv = cmul(pget(a, r >> 1, c2 >> 1), pget(b2, r & 1, c2 & 1));
            ov += Kv.re * Rv.re + Kv.im * Rv.im;
        }
    ov *= 0.25f;
    if (ov > 0.5f) { CIDX[pr] = cand; CSGN[pr] = 1.f; }
    else if (ov < -0.5f) { CIDX[pr] = cand; CSGN[pr] = -1.f; }
}

// ws float layout: AF (4096 int slots) | Rg[16*729] | DD[65536] | FLAGS[64]
#define OFF_AF   0
#define OFF_R    4096
#define OFF_DD   (4096 + 16 * 729)
#define OFF_FLAG (OFF_DD + 65536)
#define WS_FLOATS_NEEDED (OFF_FLAG + 64)

__device__ __forceinline__ int ring_conj(int cur, int r, const int* CIDX,
                                         const float* CSGN, float& sg) {
    for (int w = 7; w >= 0; --w) {
        const int tw = (w + r) & 7;
        const int pc = (cur >> (2 * w)) & 3;
        const int pt = (cur >> (2 * tw)) & 3;
        const int q = pc * 4 + pt;
        const int nq = CIDX[q];
        sg *= CSGN[q];
        cur = (cur & ~((3 << (2 * w)) | (3 << (2 * tw))))
            | ((nq >> 2) << (2 * w)) | ((nq & 3) << (2 * tw));
    }
    return cur;
}

template <int SLP>
__device__ __forceinline__ void spin_on(int* p) {
    while (__hip_atomic_load(p, __ATOMIC_ACQUIRE, __HIP_MEMORY_SCOPE_AGENT)
           != MAGIC) {
        __builtin_amdgcn_s_sleep(SLP);
    }
}

template <int Q>
__device__ __forceinline__ v8hf build_bfrag(const float* m5v, const float* m6v,
                                            const float* m7v) {
    v8hf bf;
#pragma unroll
    for (int jj = 0; jj < 8; ++jj) {
        const int j = Q * 8 + jj;
        float v = 0.f;
        if (j < 27) {
            const int k5 = j / 9, k6 = (j % 9) / 3, k7 = j % 3;
            v = m5v[k5] * m6v[k6] * m7v[k7];
        }
        bf[jj] = (_Float16)v;
    }
    return bf;
}

template <int Q>
__device__ __forceinline__ float contract_f1(const v4f* acc, const float* U9,
                                             const float* R27) {
    float ev = 0.f;
#pragma unroll
    for (int t = 0; t < 16; ++t) {
#pragma unroll
        for (int s = 0; s < 4; ++s) {
            const int i = 16 * t + 4 * Q + s;
            if (i < 243)
                ev = fmaf(U9[i / 27] * R27[i % 27], acc[t][s], ev);
        }
    }
    return ev;
}

// ---------------------------------------------------------------------------
__global__ __launch_bounds__(256, 2) void k_all(const float* __restrict__ x,
                                                const float* __restrict__ theta,
                                                float* __restrict__ ws,
                                                float* __restrict__ out,
                                                int ngroups) {
    __shared__ float SH[8960];
    __shared__ int   S1k, S1n;
    __shared__ float S1sgn;
    __shared__ int   S1w[8], S1l[8];

    const int tid = threadIdx.x;
    const int blk = blockIdx.x;
    float* Rg = ws + OFF_R;
    float* DD = ws + OFF_DD;
    int*   FL = (int*)(ws + OFF_FLAG);
    int*   AFg = (int*)(ws + OFF_AF);

    if (blk < 16) {
        float* TR   = SH;               // 256
        float* CSGN = SH + 256;         // 16
        int*   CIDX = (int*)(SH + 272); // 16
        float* Wa   = SH + 288;         // 4096
        float* Wb   = SH + 4384;        // 3072

        // ---- phase 1: zero own DD slice, publish flagZ ----
        for (int i = tid; i < 4096; i += 256)
            __hip_atomic_store(&DD[blk * 4096 + i], 0.f,
                               __ATOMIC_RELAXED, __HIP_MEMORY_SCOPE_AGENT);
        __syncthreads();
        if (tid == 0)
            __hip_atomic_store(&FL[blk], MAGIC,
                               __ATOMIC_RELEASE, __HIP_MEMORY_SCOPE_AGENT);

        // ---- tables (parallel, spill-free; verified r7) ----
        TR[tid] = ptm_entry(theta, tid >> 4, (tid >> 2) & 3, tid & 3);
        cnot_entry(tid >> 4, tid & 15, CIDX, CSGN);
        __syncthreads();

        // ---- stage 0: S1 = Ring2^dag Z0 Ring2 ----
        if (tid == 0) {
            float sg = 1.f;
            int cur = ring_conj(3, 2, CIDX, CSGN, sg);
            int k = 0;
            for (int w = 0; w < 8; ++w) {
                const int ltr = (cur >> (2 * w)) & 3;
                if (ltr != 0) { S1w[k] = w; S1l[k] = ltr; ++k; }
            }
            int n = 1;
            for (int i = 0; i < k; ++i) n *= 3;
            S1sgn = sg; S1k = k; S1n = n;
        }
        if (tid < 16) spin_on<1>(&FL[tid]);
        __syncthreads();
        const int k1 = S1k, n1 = S1n;

        // ---- phase 2: enumerate OWN 1/16 slice, expand+conj, scatter ----
        const int per = (n1 + 15) >> 4;
        const int lo = blk * per;
        const int hi = (lo + per < n1) ? (lo + per) : n1;
        for (int t = lo + tid; t < hi; t += 256) {
            float c = S1sgn;
            int s = 0;
            int tt = t;
            for (int i = 0; i < k1; ++i) {
                const int bl = tt % 3 + 1;  // X=1,Y=2,Z=3
                tt /= 3;
                c *= TR[(8 + S1w[i]) * 16 + S1l[i] * 4 + bl];
                s |= bl << (2 * S1w[i]);
            }
            float sg = 1.f;
            s = ring_conj(s, 1, CIDX, CSGN, sg);
            c *= sg;
            const int sub = (s & 3) * 4 + ((s >> 2) & 3);
            int d4 = 0;
#pragma unroll
            for (int w = 2; w < 8; ++w)
                d4 |= ((s >> (2 * w)) & 3) << (2 * (7 - w));
            __hip_atomic_store(&DD[sub * 4096 + d4], c,
                               __ATOMIC_RELAXED, __HIP_MEMORY_SCOPE_AGENT);
        }
        __syncthreads();
        if (tid == 0)
            __hip_atomic_store(&FL[16 + blk], MAGIC,
                               __ATOMIC_RELEASE, __HIP_MEMORY_SCOPE_AGENT);
        if (tid < 16) spin_on<1>(&FL[16 + tid]);
        __syncthreads();

        // ---- phase 3: gather own sub-tensor, 6-stage transform ----
        for (int i = tid; i < 4096; i += 256)
            Wa[i] = __hip_atomic_load(&DD[blk * 4096 + i],
                                      __ATOMIC_RELAXED, __HIP_MEMORY_SCOPE_AGENT);
        __syncthreads();
        const int P3c[6] = {1, 3, 9, 27, 81, 243};
        const int N4c[6] = {1024, 256, 64, 16, 4, 1};
#pragma unroll
        for (int tl = 0; tl < 6; ++tl) {
            const int w = 7 - tl;
            const float* src = (tl & 1) ? Wb : Wa;
            float* dst = (tl & 1) ? Wa : Wb;
            const int p3 = P3c[tl];
            const int Nout = p3 * 3 * N4c[tl];
            for (int idx = tid; idx < Nout; idx += 256) {
                const int q3 = idx % p3;
                const int rest = idx / p3;
                const int P = rest % 3;
                const int r = rest / 3;
                const int let = (P == 0) ? 0 : ((P == 1) ? 3 : 2);
                const float* ib = src + q3 + p3 * 4 * r;
                dst[idx] = ib[0] * TR[w * 16 + 0 + let]
                         + ib[p3] * TR[w * 16 + 4 + let]
                         + ib[2 * p3] * TR[w * 16 + 8 + let]
                         + ib[3 * p3] * TR[w * 16 + 12 + let];
            }
            __syncthreads();
        }
        for (int k = tid; k < 729; k += 256)
            __hip_atomic_store(&Rg[blk * 729 + k], Wa[k],
                               __ATOMIC_RELAXED, __HIP_MEMORY_SCOPE_AGENT);
        __syncthreads();
        if (tid == 0)
            __hip_atomic_store(&FL[32 + blk], MAGIC,
                               __ATOMIC_RELEASE, __HIP_MEMORY_SCOPE_AGENT);
    } else if (blk == 16) {
        // ---- finalizer ----
        float* BIG = SH;          // 8748
        float* TRw = SH + 8748;   // 32
        if (tid < 32)
            TRw[tid] = ptm_entry(theta, tid >> 4, (tid >> 2) & 3, tid & 3);
        if (tid < 16) spin_on<2>(&FL[32 + tid]);
        __syncthreads();

        for (int idx1 = tid; idx1 < 8748; idx1 += 256) {
            const int a0 = idx1 / 2187;
            const int rem = idx1 % 2187;
            const int P1 = rem / 729;
            const int qq = rem % 729;
            const int let = (P1 == 0) ? 0 : ((P1 == 1) ? 3 : 2);
            float v = 0.f;
#pragma unroll
            for (int a1 = 0; a1 < 4; ++a1)
                v += __hip_atomic_load(&Rg[(a0 * 4 + a1) * 729 + qq],
                                       __ATOMIC_RELAXED, __HIP_MEMORY_SCOPE_AGENT)
                     * TRw[16 + a1 * 4 + let];
            BIG[idx1] = v;
        }
        __syncthreads();

        for (int u = tid; u < 4096; u += 256) {
            const int t = u >> 8;
            const int lane = (u >> 2) & 63;
            const int jj0 = (u & 3) * 2;
            const int m = lane & 15;
            const int i = t * 16 + m;
            const int jb = (lane >> 4) * 8;
            unsigned int packed = 0;
#pragma unroll
            for (int z = 0; z < 2; ++z) {
                const int j = jb + jj0 + z;
                float v = 0.f;
                if (i < 243 && j < 27) {
                    const int idxF = i * 27 + j;
                    const int P0 = idxF / 2187;
                    const int rest = idxF % 2187;
                    const int let = (P0 == 0) ? 0 : ((P0 == 1) ? 3 : 2);
                    v = BIG[rest] * TRw[0 + let]
                      + BIG[2187 + rest] * TRw[4 + let]
                      + BIG[2 * 2187 + rest] * TRw[8 + let]
                      + BIG[3 * 2187 + rest] * TRw[12 + let];
                }
                const _Float16 hv = (_Float16)v;
                const unsigned short bits = __builtin_bit_cast(unsigned short, hv);
                packed |= ((unsigned int)bits) << (16 * z);
            }
            __hip_atomic_store(&AFg[u], (int)packed,
                               __ATOMIC_RELAXED, __HIP_MEMORY_SCOPE_AGENT);
        }
        __syncthreads();
        if (tid == 0)
            __hip_atomic_store(&FL[48], MAGIC,
                               __ATOMIC_RELEASE, __HIP_MEMORY_SCOPE_AGENT);
    }

    // ================= main phase (all 512 blocks) =================
    if (tid == 0) spin_on<8>(&FL[48]);
    __syncthreads();

    // stage AF via LDS (relaxed atomic loads -> cross-XCD safe)
    int* AFl = (int*)SH;
    for (int u = tid; u < 4096; u += 256)
        AFl[u] = __hip_atomic_load(&AFg[u],
                                   __ATOMIC_RELAXED, __HIP_MEMORY_SCOPE_AGENT);
    __syncthreads();

    const int lane = tid & 63;
    const int q = lane >> 4, e = lane & 15;
    const v8hf* AFp = (const v8hf*)SH;
    v8hf af[16];
#pragma unroll
    for (int t = 0; t < 16; ++t) af[t] = AFp[t * 64 + lane];

    const int wslot = blk * 4 + (tid >> 6);
    for (int gi = 0; gi < 4; ++gi) {
        const int g = wslot * 4 + gi;
        if (g >= ngroups) break;
        const int b = g * 16 + e;
        const float4* xp = (const float4*)(x + (size_t)b * 8);
        const float4 xa = xp[0], xb = xp[1];

        float m0v[3], m1v[3], m2v[3], m3v[3], m4v[3], m5v[3], m6v[3], m7v[3];
        m0v[0] = 1.f; m0v[1] = __cosf(xa.x); m0v[2] = -__sinf(xa.x);
        m1v[0] = 1.f; m1v[1] = __cosf(xa.y); m1v[2] = -__sinf(xa.y);
        m2v[0] = 1.f; m2v[1] = __cosf(xa.z); m2v[2] = -__sinf(xa.z);
        m3v[0] = 1.f; m3v[1] = __cosf(xa.w); m3v[2] = -__sinf(xa.w);
        m4v[0] = 1.f; m4v[1] = __cosf(xb.x); m4v[2] = -__sinf(xb.x);
        m5v[0] = 1.f; m5v[1] = __cosf(xb.y); m5v[2] = -__sinf(xb.y);
        m6v[0] = 1.f; m6v[1] = __cosf(xb.z); m6v[2] = -__sinf(xb.z);
        m7v[0] = 1.f; m7v[1] = __cosf(xb.w); m7v[2] = -__sinf(xb.w);

        v8hf bf;
        if (q == 0)      bf = build_bfrag<0>(m5v, m6v, m7v);
        else if (q == 1) bf = build_bfrag<1>(m5v, m6v, m7v);
        else if (q == 2) bf = build_bfrag<2>(m5v, m6v, m7v);
        else             bf = build_bfrag<3>(m5v, m6v, m7v);

        float U9[9], R27[27];
#pragma unroll
        for (int a = 0; a < 3; ++a)
#pragma unroll
            for (int b2 = 0; b2 < 3; ++b2) {
                U9[a * 3 + b2] = m0v[a] * m1v[b2];
                const float p23 = m2v[a] * m3v[b2];
#pragma unroll
                for (int c2 = 0; c2 < 3; ++c2)
                    R27[(a * 3 + b2) * 3 + c2] = p23 * m4v[c2];
            }

        const v4f zero = {0.f, 0.f, 0.f, 0.f};
        v4f acc[16];
#pragma unroll
        for (int t = 0; t < 16; ++t)
            acc[t] = __builtin_amdgcn_mfma_f32_16x16x32_f16(af[t], bf, zero, 0, 0, 0);

        float ev;
        if (q == 0)      ev = contract_f1<0>(acc, U9, R27);
        else if (q == 1) ev = contract_f1<1>(acc, U9, R27);
        else if (q == 2) ev = contract_f1<2>(acc, U9, R27);
        else             ev = contract_f1<3>(acc, U9, R27);

        ev += __shfl_xor(ev, 16, 64);
        ev += __shfl_xor(ev, 32, 64);
        if (lane < 16) out[b] = (ev + 1.f) * 0.5f;
    }
}

// ============================================================================
// Fallback: round-1 direct statevector simulator (used if ws too small).
// ============================================================================
struct c32 { float x, y; };

__device__ __forceinline__ c32 shfl_xor_c(c32 v, int mask) {
    c32 r;
    r.x = __shfl_xor(v.x, mask, 64);
    r.y = __shfl_xor(v.y, mask, 64);
    return r;
}
__device__ __forceinline__ c32 cmadd2(c32 ga, c32 a, c32 gp, c32 p) {
    c32 n;
    n.x = ga.x * a.x - ga.y * a.y + gp.x * p.x - gp.y * p.y;
    n.y = ga.x * a.y + ga.y * a.x + gp.x * p.y + gp.y * p.x;
    return n;
}
__device__ __forceinline__ c32 rx_mix(float c, float s, c32 a, c32 p) {
    c32 n;
    n.x = c * a.x + s * p.y;
    n.y = c * a.y - s * p.x;
    return n;
}
__device__ __forceinline__ void apply_rx(c32 st[4], int lane, int bb, float c, float s) {
    if (bb < 6) {
#pragma unroll
        for (int r = 0; r < 4; ++r) {
            c32 p = shfl_xor_c(st[r], 1 << bb);
            st[r] = rx_mix(c, s, st[r], p);
        }
    } else if (bb == 6) {
        c32 n0 = rx_mix(c, s, st[0], st[1]);
        c32 n1 = rx_mix(c, s, st[1], st[0]);
        c32 n2 = rx_mix(c, s, st[2], st[3]);
        c32 n3 = rx_mix(c, s, st[3], st[2]);
        st[0] = n0; st[1] = n1; st[2] = n2; st[3] = n3;
    } else {
        c32 n0 = rx_mix(c, s, st[0], st[2]);
        c32 n2 = rx_mix(c, s, st[2], st[0]);
        c32 n1 = rx_mix(c, s, st[1], st[3]);
        c32 n3 = rx_mix(c, s, st[3], st[1]);
        st[0] = n0; st[1] = n1; st[2] = n2; st[3] = n3;
    }
}
__device__ __forceinline__ void apply_rot(c32 st[4], int lane, int bb,
                                          c32 g00, c32 g01, c32 g10, c32 g11) {
    if (bb < 6) {
#pragma unroll
        for (int r = 0; r < 4; ++r) {
            c32 p = shfl_xor_c(st[r], 1 << bb);
            bool hi = (lane >> bb) & 1;
            c32 ga, gp;
            ga.x = hi ? g11.x : g00.x;
            ga.y = hi ? g11.y : g00.y;
            gp.x = hi ? g10.x : g01.x;
            gp.y = hi ? g10.y : g01.y;
            st[r] = cmadd2(ga, st[r], gp, p);
        }
    } else if (bb == 6) {
        c32 n0 = cmadd2(g00, st[0], g01, st[1]);
        c32 n1 = cmadd2(g10, st[0], g11, st[1]);
        c32 n2 = cmadd2(g00, st[2], g01, st[3]);
        c32 n3 = cmadd2(g10, st[2], g11, st[3]);
        st[0] = n0; st[1] = n1; st[2] = n2; st[3] = n3;
    } else {
        c32 n0 = cmadd2(g00, st[0], g01, st[2]);
        c32 n2 = cmadd2(g10, st[0], g11, st[2]);
        c32 n1 = cmadd2(g00, st[1], g01, st[3]);
        c32 n3 = cmadd2(g10, st[1], g11, st[3]);
        st[0] = n0; st[1] = n1; st[2] = n2; st[3] = n3;
    }
}
__device__ __forceinline__ void cswap(bool c, c32& a, c32& b) {
    c32 t = a;
    a.x = c ? b.x : a.x; a.y = c ? b.y : a.y;
    b.x = c ? t.x : b.x; b.y = c ? t.y : b.y;
}
__device__ __forceinline__ void apply_cnot(c32 st[4], int lane, int bc, int bt) {
    if (bt < 6) {
        if (bc < 6) {
            bool ctrl = (lane >> bc) & 1;
#pragma unroll
            for (int r = 0; r < 4; ++r) {
                c32 p = shfl_xor_c(st[r], 1 << bt);
                st[r].x = ctrl ? p.x : st[r].x;
                st[r].y = ctrl ? p.y : st[r].y;
            }
        } else {
#pragma unroll
            for (int r = 0; r < 4; ++r) {
                if ((r >> (bc - 6)) & 1) st[r] = shfl_xor_c(st[r], 1 << bt);
            }
        }
    } else {
        if (bc < 6) {
            bool ctrl = (lane >> bc) & 1;
            if (bt == 6) { cswap(ctrl, st[0], st[1]); cswap(ctrl, st[2], st[3]); }
            else         { cswap(ctrl, st[0], st[2]); cswap(ctrl, st[1], st[3]); }
        } else {
            if (bc == 7 && bt == 6) { c32 t = st[2]; st[2] = st[3]; st[3] = t; }
            else if (bc == 6 && bt == 7) { c32 t = st[1]; st[1] = st[3]; st[3] = t; }
        }
    }
}
__global__ __launch_bounds__(256) void qsim_kernel(const float* __restrict__ x,
                                                   const float* __restrict__ theta,
                                                   float* __restrict__ out,
                                                   int batch) {
    __shared__ float rot[2 * 8 * 8];
    const int t = threadIdx.x;
    if (t < 16) {
        const int l = t >> 3, w = t & 7;
        const float phi = theta[(l * 8 + w) * 3 + 0];
        const float th  = theta[(l * 8 + w) * 3 + 1];
        const float om  = theta[(l * 8 + w) * 3 + 2];
        const float c = cosf(0.5f * th), s = sinf(0.5f * th);
        const float p = 0.5f * (phi + om), m = 0.5f * (phi - om);
        float* g = &rot[t * 8];
        g[0] = c * cosf(p);  g[1] = -c * sinf(p);
        g[2] = -s * cosf(m); g[3] = -s * sinf(m);
        g[4] = s * cosf(m);  g[5] = -s * sinf(m);
        g[6] = c * cosf(p);  g[7] = c * sinf(p);
    }
    __syncthreads();
    const int lane = t & 63;
    const int b = blockIdx.x * 4 + (t >> 6);
    if (b >= batch) return;
    float c8 = 0.f, s8 = 0.f;
    if (lane < 8) {
        const float xv = 0.5f * x[b * 8 + lane];
        c8 = cosf(xv); s8 = sinf(xv);
    }
    c32 st[4];
#pragma unroll
    for (int r = 0; r < 4; ++r) { st[r].x = 0.f; st[r].y = 0.f; }
    if (lane == 0) st[0].x = 1.f;
#pragma unroll
    for (int w = 0; w < 8; ++w) {
        const float c = __shfl(c8, w, 64);
        const float s = __shfl(s8, w, 64);
        apply_rx(st, lane, 7 - w, c, s);
    }
#pragma unroll
    for (int l = 0; l < 2; ++l) {
#pragma unroll
        for (int w = 0; w < 8; ++w) {
            const float* g = &rot[(l * 8 + w) * 8];
            c32 g00{g[0], g[1]}, g01{g[2], g[3]}, g10{g[4], g[5]}, g11{g[6], g[7]};
            apply_rot(st, lane, 7 - w, g00, g01, g10, g11);
        }
        const int rr = l + 1;
#pragma unroll
        for (int w = 0; w < 8; ++w) apply_cnot(st, lane, 7 - w, 7 - ((w + rr) & 7));
    }
    float v = st[0].x * st[0].x + st[0].y * st[0].y
            + st[1].x * st[1].x + st[1].y * st[1].y
            - st[2].x * st[2].x - st[2].y * st[2].y
            - st[3].x * st[3].x - st[3].y * st[3].y;
#pragma unroll
    for (int off = 32; off > 0; off >>= 1) v += __shfl_xor(v, off, 64);
    if (lane == 0) out[b] = (v + 1.f) * 0.5f;
}

// ============================================================================
extern "C" void kernel_launch(void* const* d_in, const int* in_sizes, int n_in,
                              void* d_out, int out_size, void* d_ws, size_t ws_size,
                              hipStream_t stream) {
    const float* x     = (const float*)d_in[0];
    const float* theta = (const float*)d_in[1];
    float* out = (float*)d_out;
    const int batch = in_sizes[0] / 8;

    if (ws_size >= (size_t)WS_FLOATS_NEEDED * 4 + 256 && (batch & 15) == 0) {
        float* ws = (float*)d_ws;
        const int ngroups = batch / 16;  // 8192
        k_all<<<dim3(512), dim3(256), 0, stream>>>(x, theta, ws, out, ngroups);
    } else {
        qsim_kernel<<<dim3((batch + 3) / 4), dim3(256), 0, stream>>>(x, theta, out, batch);
    }
}

// Round 10
// 76.950 us; speedup vs baseline: 2.7919x; 2.7919x over previous
//
#include <hip/hip_runtime.h>

// ============================================================================
// ev(b) = F1(b)^T * A * F2(b); A fixed (theta batch-uniform), F = cos/sin
// tensor factors. Two launches:
//  k_prep2 (17 blocks x 1024): blocks 0-15 build per-(wire0,wire1) sub-tensors
//    (round-6-verified pipeline) -> Rg + flag; block 16 spins on 16 flags,
//    finalizes wire-1/wire-0, packs AF in 27-tile NON-DIVERGENT layout:
//    tile t=(k2,k3,k4), row m=4*k0+k1 (q=k0, s=k1), k-slot j=(k5k6k7).
//  k_main6 (512 x 256): AF staged to LDS; per group 27 MFMAs; contract uses
//    only compile-time indices (no lane divergence); 4 groups/wave.
// ============================================================================

typedef _Float16 v8hf __attribute__((ext_vector_type(8)));
typedef float v4f __attribute__((ext_vector_type(4)));

#define MAGIC 0x13572468

struct cpx { float re, im; };
__device__ __forceinline__ cpx cmul(cpx a, cpx b) {
    return {a.re * b.re - a.im * b.im, a.re * b.im + a.im * b.re};
}

__device__ __forceinline__ cpx pget(int a, int i, int j) {
    static const float RE[4][4] = {{1, 0, 0, 1}, {0, 1, 1, 0},
                                   {0, 0, 0, 0}, {1, 0, 0, -1}};
    static const float IM[4][4] = {{0, 0, 0, 0}, {0, 0, 0, 0},
                                   {0, -1, 1, 0}, {0, 0, 0, 0}};
    cpx r; r.re = RE[a][i * 2 + j]; r.im = IM[a][i * 2 + j];
    return r;
}

__device__ float ptm_entry(const float* __restrict__ theta, int g, int a, int b) {
    const int l = g >> 3, w = g & 7;
    const float phi = theta[(l * 8 + w) * 3 + 0];
    const float th  = theta[(l * 8 + w) * 3 + 1];
    const float om  = theta[(l * 8 + w) * 3 + 2];
    const float c = cosf(0.5f * th), s = sinf(0.5f * th);
    const float ps = 0.5f * (phi + om), ms = 0.5f * (phi - om);
    cpx G[2][2];
    G[0][0] = {c * cosf(ps), -c * sinf(ps)};
    G[0][1] = {-s * cosf(ms), -s * sinf(ms)};
    G[1][0] = {s * cosf(ms), -s * sinf(ms)};
    G[1][1] = {c * cosf(ps), c * sinf(ps)};
    cpx M1[2][2], H[2][2];
#pragma unroll
    for (int i = 0; i < 2; ++i)
#pragma unroll
        for (int j = 0; j < 2; ++j) {
            cpx acc{0.f, 0.f};
#pragma unroll
            for (int k = 0; k < 2; ++k) {
                cpx t = cmul(pget(a, i, k), G[k][j]);
                acc.re += t.re; acc.im += t.im;
            }
            M1[i][j] = acc;
        }
#pragma unroll
    for (int i = 0; i < 2; ++i)
#pragma unroll
        for (int j = 0; j < 2; ++j) {
            cpx acc{0.f, 0.f};
#pragma unroll
            for (int k = 0; k < 2; ++k) {
                cpx gc{G[k][i].re, -G[k][i].im};
                cpx t = cmul(gc, M1[k][j]);
                acc.re += t.re; acc.im += t.im;
            }
            H[i][j] = acc;
        }
    float tr = 0.f;
#pragma unroll
    for (int i = 0; i < 2; ++i)
#pragma unroll
        for (int j = 0; j < 2; ++j) {
            cpx pb = pget(b, i, j);
            tr += pb.re * H[j][i].re - pb.im * H[j][i].im;
        }
    return 0.5f * tr;
}

__device__ void cnot_entry(int pr, int cand, int* CIDX, float* CSGN) {
    const int pc = pr >> 2, pt = pr & 3;
    const int a = cand >> 2, b2 = cand & 3;
    const int perm[4] = {0, 1, 3, 2};
    float ov = 0.f;
#pragma unroll
    for (int r = 0; r < 4; ++r)
#pragma unroll
        for (int c2 = 0; c2 < 4; ++c2) {
            const int rp = perm[r], cp = perm[c2];
            cpx Rv = cmul(pget(pc, rp >> 1, cp >> 1), pget(pt, rp & 1, cp & 1));
            cpx Kv = cmul(pget(a, r >> 1, c2 >> 1), pget(b2, r & 1, c2 & 1));
            ov += Kv.re * Rv.re + Kv.im * Rv.im;
        }
    ov *= 0.25f;
    if (ov > 0.5f) { CIDX[pr] = cand; CSGN[pr] = 1.f; }
    else if (ov < -0.5f) { CIDX[pr] = cand; CSGN[pr] = -1.f; }
}

// ws float layout: AF (6912 int slots, 27 tiles) | Rg[16*729] | FLAGS[16]
#define OFF_AF   0
#define OFF_R    6912
#define OFF_FLAG (6912 + 16 * 729)
#define WS_FLOATS_NEEDED (OFF_FLAG + 16)

__device__ __forceinline__ int ring_conj(int cur, int r, const int* CIDX,
                                         const float* CSGN, float& sg) {
    for (int w = 7; w >= 0; --w) {
        const int tw = (w + r) & 7;
        const int pc = (cur >> (2 * w)) & 3;
        const int pt = (cur >> (2 * tw)) & 3;
        const int q = pc * 4 + pt;
        const int nq = CIDX[q];
        sg *= CSGN[q];
        cur = (cur & ~((3 << (2 * w)) | (3 << (2 * tw))))
            | ((nq >> 2) << (2 * w)) | ((nq & 3) << (2 * tw));
    }
    return cur;
}

template <int SLP>
__device__ __forceinline__ void spin_on(int* p) {
    while (__hip_atomic_load(p, __ATOMIC_ACQUIRE, __HIP_MEMORY_SCOPE_AGENT)
           != MAGIC) {
        __builtin_amdgcn_s_sleep(SLP);
    }
}

// ---------------------------------------------------------------------------
// k_prep2: 17 blocks x 1024.
// ---------------------------------------------------------------------------
__global__ __launch_bounds__(1024) void k_prep2(const float* __restrict__ theta,
                                                float* __restrict__ ws) {
    __shared__ float SH[8780];
    __shared__ int   S1k, S1n;
    __shared__ float S1sgn;
    __shared__ int   S1w[8], S1l[8];

    const int tid = threadIdx.x;
    const int blk = blockIdx.x;
    float* Rg = ws + OFF_R;
    int*   FL = (int*)(ws + OFF_FLAG);

    if (blk < 16) {
        float* TR   = SH;               // 256
        float* CSGN = SH + 256;         // 16
        int*   CIDX = (int*)(SH + 272); // 16
        float* Wa   = SH + 288;         // 4096
        float* Wb   = SH + 4384;        // 3072
        const int sa0 = blk >> 2, sa1 = blk & 3;

        if (tid < 256) TR[tid] = ptm_entry(theta, tid >> 4, (tid >> 2) & 3, tid & 3);
        else if (tid < 512) {
            const int r = tid - 256;
            cnot_entry(r >> 4, r & 15, CIDX, CSGN);
        }
        for (int i = tid; i < 4096; i += 1024) Wa[i] = 0.f;
        __syncthreads();

        if (tid == 0) {
            float sg = 1.f;
            int cur = ring_conj(3 /* Z wire0 */, 2, CIDX, CSGN, sg);
            int k = 0;
            for (int w = 0; w < 8; ++w) {
                const int ltr = (cur >> (2 * w)) & 3;
                if (ltr != 0) { S1w[k] = w; S1l[k] = ltr; ++k; }
            }
            int n = 1;
            for (int i = 0; i < k; ++i) n *= 3;
            S1sgn = sg; S1k = k; S1n = n;
        }
        __syncthreads();
        const int k1 = S1k, n1 = S1n;

        // enumerate all strings, keep those matching this block's (w0,w1)
        for (int t = tid; t < n1; t += 1024) {
            float c = S1sgn;
            int s = 0;
            int tt = t;
            for (int i = 0; i < k1; ++i) {
                const int bl = tt % 3 + 1;
                tt /= 3;
                c *= TR[(8 + S1w[i]) * 16 + S1l[i] * 4 + bl];
                s |= bl << (2 * S1w[i]);
            }
            float sg = 1.f;
            s = ring_conj(s, 1, CIDX, CSGN, sg);
            c *= sg;
            if (((s & 3) == sa0) && (((s >> 2) & 3) == sa1)) {
                int d4 = 0;
#pragma unroll
                for (int w = 2; w < 8; ++w)
                    d4 |= ((s >> (2 * w)) & 3) << (2 * (7 - w));
                Wa[d4] = c;
            }
        }
        __syncthreads();

        const int P3c[6] = {1, 3, 9, 27, 81, 243};
        const int N4c[6] = {1024, 256, 64, 16, 4, 1};
#pragma unroll
        for (int tl = 0; tl < 6; ++tl) {
            const int w = 7 - tl;
            const float* src = (tl & 1) ? Wb : Wa;
            float* dst = (tl & 1) ? Wa : Wb;
            const int p3 = P3c[tl];
            const int Nout = p3 * 3 * N4c[tl];
            for (int idx = tid; idx < Nout; idx += 1024) {
                const int q3 = idx % p3;
                const int rest = idx / p3;
                const int P = rest % 3;
                const int r = rest / 3;
                const int let = (P == 0) ? 0 : ((P == 1) ? 3 : 2);
                const float* ib = src + q3 + p3 * 4 * r;
                dst[idx] = ib[0] * TR[w * 16 + 0 + let]
                         + ib[p3] * TR[w * 16 + 4 + let]
                         + ib[2 * p3] * TR[w * 16 + 8 + let]
                         + ib[3 * p3] * TR[w * 16 + 12 + let];
            }
            __syncthreads();
        }
        for (int k = tid; k < 729; k += 1024)
            __hip_atomic_store(&Rg[blk * 729 + k], Wa[k],
                               __ATOMIC_RELAXED, __HIP_MEMORY_SCOPE_AGENT);
        __syncthreads();
        if (tid == 0)
            __hip_atomic_store(&FL[blk], MAGIC,
                               __ATOMIC_RELEASE, __HIP_MEMORY_SCOPE_AGENT);
    } else {
        // ---- finalizer block ----
        float* BIG = SH;          // 8748
        float* TRw = SH + 8748;   // 32
        if (tid < 32)
            TRw[tid] = ptm_entry(theta, tid >> 4, (tid >> 2) & 3, tid & 3);
        if (tid < 16) spin_on<2>(&FL[tid]);
        __syncthreads();

        // wire-1 transform
        for (int idx1 = tid; idx1 < 8748; idx1 += 1024) {
            const int a0 = idx1 / 2187;
            const int rem = idx1 % 2187;
            const int P1 = rem / 729;
            const int qq = rem % 729;
            const int let = (P1 == 0) ? 0 : ((P1 == 1) ? 3 : 2);
            float v = 0.f;
#pragma unroll
            for (int a1 = 0; a1 < 4; ++a1)
                v += __hip_atomic_load(&Rg[(a0 * 4 + a1) * 729 + qq],
                                       __ATOMIC_RELAXED, __HIP_MEMORY_SCOPE_AGENT)
                     * TRw[16 + a1 * 4 + let];
            BIG[idx1] = v;
        }
        __syncthreads();

        // wire-0 transform + pack 27-tile AF:
        // tile t=(k2k3k4), row m=4*k0+k1 (k0,k1<3), k-slot j=(k5k6k7)<27.
        int* AFi = (int*)(ws + OFF_AF);
        for (int u = tid; u < 6912; u += 1024) {
            const int t = u >> 8;             // 0..26
            const int rem = u & 255;
            const int lane = rem >> 2;
            const int jj0 = (rem & 3) * 2;
            const int m = lane & 15;
            const int q0 = m >> 2, s0 = m & 3;
            const int jb = (lane >> 4) * 8;
            unsigned int packed = 0;
#pragma unroll
            for (int z = 0; z < 2; ++z) {
                const int j = jb + jj0 + z;
                float v = 0.f;
                if (q0 < 3 && s0 < 3 && j < 27) {
                    const int i = q0 * 81 + s0 * 27 + t;
                    const int idxF = i * 27 + j;
                    const int P0 = idxF / 2187;
                    const int rest2 = idxF % 2187;
                    const int let = (P0 == 0) ? 0 : ((P0 == 1) ? 3 : 2);
                    v = BIG[rest2] * TRw[0 + let]
                      + BIG[2187 + rest2] * TRw[4 + let]
                      + BIG[2 * 2187 + rest2] * TRw[8 + let]
                      + BIG[3 * 2187 + rest2] * TRw[12 + let];
                }
                const _Float16 hv = (_Float16)v;
                const unsigned short bits = __builtin_bit_cast(unsigned short, hv);
                packed |= ((unsigned int)bits) << (16 * z);
            }
            AFi[u] = (int)packed;
        }
    }
}

// ---------------------------------------------------------------------------
// k_main6: non-divergent contraction. 512 blocks x 256; 4 groups/wave.
// ---------------------------------------------------------------------------
__global__ __launch_bounds__(256) void k_main6(const float* __restrict__ x,
                                               const int* __restrict__ wsAF,
                                               float* __restrict__ out,
                                               int ngroups) {
    __shared__ int AFl[6912];
    const int tid = threadIdx.x;
    for (int u = tid; u < 6912; u += 256) AFl[u] = wsAF[u];
    __syncthreads();

    const int lane = tid & 63;
    const int q = lane >> 4, e = lane & 15;
    const v8hf* AFp = (const v8hf*)AFl;
    const int wave = blockIdx.x * 4 + (tid >> 6);
    const bool q0b = (q == 0), q1b = (q == 1), q2b = (q == 2);

    for (int gi = 0; gi < 4; ++gi) {
        const int g = wave * 4 + gi;
        if (g >= ngroups) break;
        const int b = g * 16 + e;
        const float4* xp = (const float4*)(x + (size_t)b * 8);
        const float4 xa = xp[0], xb = xp[1];

        float cw[8], msw[8];
        {
            const float xs[8] = {xa.x, xa.y, xa.z, xa.w, xb.x, xb.y, xb.z, xb.w};
#pragma unroll
            for (int w = 0; w < 8; ++w) {
                float sv, cv;
                __sincosf(xs[w], &sv, &cv);
                cw[w] = cv;
                msw[w] = -sv;
            }
        }

        // full F2[27] (wires 5,6,7), then per-slot q-select (no divergence)
        float F2[27];
        {
            const float m5v[3] = {1.f, cw[5], msw[5]};
            const float m6v[3] = {1.f, cw[6], msw[6]};
            const float m7v[3] = {1.f, cw[7], msw[7]};
#pragma unroll
            for (int a = 0; a < 3; ++a)
#pragma unroll
                for (int b2 = 0; b2 < 3; ++b2) {
                    const float p = m5v[a] * m6v[b2];
#pragma unroll
                    for (int c2 = 0; c2 < 3; ++c2)
                        F2[(a * 3 + b2) * 3 + c2] = p * m7v[c2];
                }
        }
        v8hf bf;
#pragma unroll
        for (int jj = 0; jj < 8; ++jj) {
            const float c0 = F2[jj];
            const float c1 = F2[jj + 8];
            const float c2 = F2[jj + 16];
            const float c3 = (jj < 3) ? F2[jj + 24] : 0.f;
            const float v = q0b ? c0 : (q1b ? c1 : (q2b ? c2 : c3));
            bf[jj] = (_Float16)v;
        }

        // 27 MFMAs; contract with compile-time indices only.
        const v4f zero = {0.f, 0.f, 0.f, 0.f};
        float h[9];
#pragma unroll
        for (int t = 0; t < 27; ++t) {
            const int a = t / 9, b2 = (t / 3) % 3, c2 = t % 3;
            v4f acc = __builtin_amdgcn_mfma_f32_16x16x32_f16(
                AFp[t * 64 + lane], bf, zero, 0, 0, 0);
            float f = fmaf(cw[1], acc[1], acc[0]);
            f = fmaf(msw[1], acc[2], f);
            if (c2 == 0)      h[a * 3 + b2] = f;
            else if (c2 == 1) h[a * 3 + b2] = fmaf(cw[4], f, h[a * 3 + b2]);
            else              h[a * 3 + b2] = fmaf(msw[4], f, h[a * 3 + b2]);
        }
        float e0 = fmaf(cw[3], h[1], h[0]); e0 = fmaf(msw[3], h[2], e0);
        float e1 = fmaf(cw[3], h[4], h[3]); e1 = fmaf(msw[3], h[5], e1);
        float e2 = fmaf(cw[3], h[7], h[6]); e2 = fmaf(msw[3], h[8], e2);
        float ev = fmaf(cw[2], e1, e0);
        ev = fmaf(msw[2], e2, ev);
        const float g0 = q0b ? 1.f : (q1b ? cw[0] : (q2b ? msw[0] : 0.f));
        ev *= g0;

        ev += __shfl_xor(ev, 16, 64);
        ev += __shfl_xor(ev, 32, 64);
        if (lane < 16) out[b] = (ev + 1.f) * 0.5f;
    }
}

// ============================================================================
// Fallback: round-1 direct statevector simulator (used if ws too small).
// ============================================================================
struct c32 { float x, y; };

__device__ __forceinline__ c32 shfl_xor_c(c32 v, int mask) {
    c32 r;
    r.x = __shfl_xor(v.x, mask, 64);
    r.y = __shfl_xor(v.y, mask, 64);
    return r;
}
__device__ __forceinline__ c32 cmadd2(c32 ga, c32 a, c32 gp, c32 p) {
    c32 n;
    n.x = ga.x * a.x - ga.y * a.y + gp.x * p.x - gp.y * p.y;
    n.y = ga.x * a.y + ga.y * a.x + gp.x * p.y + gp.y * p.x;
    return n;
}
__device__ __forceinline__ c32 rx_mix(float c, float s, c32 a, c32 p) {
    c32 n;
    n.x = c * a.x + s * p.y;
    n.y = c * a.y - s * p.x;
    return n;
}
__device__ __forceinline__ void apply_rx(c32 st[4], int lane, int bb, float c, float s) {
    if (bb < 6) {
#pragma unroll
        for (int r = 0; r < 4; ++r) {
            c32 p = shfl_xor_c(st[r], 1 << bb);
            st[r] = rx_mix(c, s, st[r], p);
        }
    } else if (bb == 6) {
        c32 n0 = rx_mix(c, s, st[0], st[1]);
        c32 n1 = rx_mix(c, s, st[1], st[0]);
        c32 n2 = rx_mix(c, s, st[2], st[3]);
        c32 n3 = rx_mix(c, s, st[3], st[2]);
        st[0] = n0; st[1] = n1; st[2] = n2; st[3] = n3;
    } else {
        c32 n0 = rx_mix(c, s, st[0], st[2]);
        c32 n2 = rx_mix(c, s, st[2], st[0]);
        c32 n1 = rx_mix(c, s, st[1], st[3]);
        c32 n3 = rx_mix(c, s, st[3], st[1]);
        st[0] = n0; st[1] = n1; st[2] = n2; st[3] = n3;
    }
}
__device__ __forceinline__ void apply_rot(c32 st[4], int lane, int bb,
                                          c32 g00, c32 g01, c32 g10, c32 g11) {
    if (bb < 6) {
#pragma unroll
        for (int r = 0; r < 4; ++r) {
            c32 p = shfl_xor_c(st[r], 1 << bb);
            bool hi = (lane >> bb) & 1;
            c32 ga, gp;
            ga.x = hi ? g11.x : g00.x;
            ga.y = hi ? g11.y : g00.y;
            gp.x = hi ? g10.x : g01.x;
            gp.y = hi ? g10.y : g01.y;
            st[r] = cmadd2(ga, st[r], gp, p);
        }
    } else if (bb == 6) {
        c32 n0 = cmadd2(g00, st[0], g01, st[1]);
        c32 n1 = cmadd2(g10, st[0], g11, st[1]);
        c32 n2 = cmadd2(g00, st[2], g01, st[3]);
        c32 n3 = cmadd2(g10, st[2], g11, st[3]);
        st[0] = n0; st[1] = n1; st[2] = n2; st[3] = n3;
    } else {
        c32 n0 = cmadd2(g00, st[0], g01, st[2]);
        c32 n2 = cmadd2(g10, st[0], g11, st[2]);
        c32 n1 = cmadd2(g00, st[1], g01, st[3]);
        c32 n3 = cmadd2(g10, st[1], g11, st[3]);
        st[0] = n0; st[1] = n1; st[2] = n2; st[3] = n3;
    }
}
__device__ __forceinline__ void cswap(bool c, c32& a, c32& b) {
    c32 t = a;
    a.x = c ? b.x : a.x; a.y = c ? b.y : a.y;
    b.x = c ? t.x : b.x; b.y = c ? t.y : b.y;
}
__device__ __forceinline__ void apply_cnot(c32 st[4], int lane, int bc, int bt) {
    if (bt < 6) {
        if (bc < 6) {
            bool ctrl = (lane >> bc) & 1;
#pragma unroll
            for (int r = 0; r < 4; ++r) {
                c32 p = shfl_xor_c(st[r], 1 << bt);
                st[r].x = ctrl ? p.x : st[r].x;
                st[r].y = ctrl ? p.y : st[r].y;
            }
        } else {
#pragma unroll
            for (int r = 0; r < 4; ++r) {
                if ((r >> (bc - 6)) & 1) st[r] = shfl_xor_c(st[r], 1 << bt);
            }
        }
    } else {
        if (bc < 6) {
            bool ctrl = (lane >> bc) & 1;
            if (bt == 6) { cswap(ctrl, st[0], st[1]); cswap(ctrl, st[2], st[3]); }
            else         { cswap(ctrl, st[0], st[2]); cswap(ctrl, st[1], st[3]); }
        } else {
            if (bc == 7 && bt == 6) { c32 t = st[2]; st[2] = st[3]; st[3] = t; }
            else if (bc == 6 && bt == 7) { c32 t = st[1]; st[1] = st[3]; st[3] = t; }
        }
    }
}
__global__ __launch_bounds__(256) void qsim_kernel(const float* __restrict__ x,
                                                   const float* __restrict__ theta,
                                                   float* __restrict__ out,
                                                   int batch) {
    __shared__ float rot[2 * 8 * 8];
    const int t = threadIdx.x;
    if (t < 16) {
        const int l = t >> 3, w = t & 7;
        const float phi = theta[(l * 8 + w) * 3 + 0];
        const float th  = theta[(l * 8 + w) * 3 + 1];
        const float om  = theta[(l * 8 + w) * 3 + 2];
        const float c = cosf(0.5f * th), s = sinf(0.5f * th);
        const float p = 0.5f * (phi + om), m = 0.5f * (phi - om);
        float* g = &rot[t * 8];
        g[0] = c * cosf(p);  g[1] = -c * sinf(p);
        g[2] = -s * cosf(m); g[3] = -s * sinf(m);
        g[4] = s * cosf(m);  g[5] = -s * sinf(m);
        g[6] = c * cosf(p);  g[7] = c * sinf(p);
    }
    __syncthreads();
    const int lane = t & 63;
    const int b = blockIdx.x * 4 + (t >> 6);
    if (b >= batch) return;
    float c8 = 0.f, s8 = 0.f;
    if (lane < 8) {
        const float xv = 0.5f * x[b * 8 + lane];
        c8 = cosf(xv); s8 = sinf(xv);
    }
    c32 st[4];
#pragma unroll
    for (int r = 0; r < 4; ++r) { st[r].x = 0.f; st[r].y = 0.f; }
    if (lane == 0) st[0].x = 1.f;
#pragma unroll
    for (int w = 0; w < 8; ++w) {
        const float c = __shfl(c8, w, 64);
        const float s = __shfl(s8, w, 64);
        apply_rx(st, lane, 7 - w, c, s);
    }
#pragma unroll
    for (int l = 0; l < 2; ++l) {
#pragma unroll
        for (int w = 0; w < 8; ++w) {
            const float* g = &rot[(l * 8 + w) * 8];
            c32 g00{g[0], g[1]}, g01{g[2], g[3]}, g10{g[4], g[5]}, g11{g[6], g[7]};
            apply_rot(st, lane, 7 - w, g00, g01, g10, g11);
        }
        const int rr = l + 1;
#pragma unroll
        for (int w = 0; w < 8; ++w) apply_cnot(st, lane, 7 - w, 7 - ((w + rr) & 7));
    }
    float v = st[0].x * st[0].x + st[0].y * st[0].y
            + st[1].x * st[1].x + st[1].y * st[1].y
            - st[2].x * st[2].x - st[2].y * st[2].y
            - st[3].x * st[3].x - st[3].y * st[3].y;
#pragma unroll
    for (int off = 32; off > 0; off >>= 1) v += __shfl_xor(v, off, 64);
    if (lane == 0) out[b] = (v + 1.f) * 0.5f;
}

// ============================================================================
extern "C" void kernel_launch(void* const* d_in, const int* in_sizes, int n_in,
                              void* d_out, int out_size, void* d_ws, size_t ws_size,
                              hipStream_t stream) {
    const float* x     = (const float*)d_in[0];
    const float* theta = (const float*)d_in[1];
    float* out = (float*)d_out;
    const int batch = in_sizes[0] / 8;

    if (ws_size >= (size_t)WS_FLOATS_NEEDED * 4 + 256 && (batch & 15) == 0) {
        float* ws = (float*)d_ws;
        k_prep2<<<dim3(17), dim3(1024), 0, stream>>>(theta, ws);
        const int ngroups = batch / 16;  // 8192
        k_main6<<<dim3(512), dim3(256), 0, stream>>>(
            x, (const int*)ws + OFF_AF, out, ngroups);
    } else {
        qsim_kernel<<<dim3((batch + 3) / 4), dim3(256), 0, stream>>>(x, theta, out, batch);
    }
}